// Round 2
// baseline (427.869 us; speedup 1.0000x reference)
//
#include <hip/hip_runtime.h>
#include <hip/hip_bf16.h>

// Reference: out = copy of signal (8192 x 8192 fp32). Pure D2D copy, 256 MiB
// read + 256 MiB write => roofline ~85 us at 6.3 TB/s achievable.
//
// R0 lesson: hipMemcpyAsync(D2D) under graph capture goes to SDMA (~1.26 TB/s
// measured). A shader float4 copy (m13 pattern, 6.29 TB/s) is ~5x faster.
// Harness's own fillBufferAligned hits 6.5 TB/s => that's the ceiling to match.

__global__ __launch_bounds__(256) void copy_f4_kernel(
    const float4* __restrict__ src, float4* __restrict__ dst, long n4) {
    long i = (long)blockIdx.x * blockDim.x + threadIdx.x;
    long stride = (long)gridDim.x * blockDim.x;
    for (; i < n4; i += stride) {
        dst[i] = src[i];
    }
}

extern "C" void kernel_launch(void* const* d_in, const int* in_sizes, int n_in,
                              void* d_out, int out_size, void* d_ws, size_t ws_size,
                              hipStream_t stream) {
    const float4* src = (const float4*)d_in[0];
    float4* dst = (float4*)d_out;
    long n4 = (long)out_size / 4;  // 8192*8192/4 = 16,777,216 float4
    // 8192 blocks x 256 threads: 8 float4/thread, 32 blocks/CU — saturates HBM.
    copy_f4_kernel<<<8192, 256, 0, stream>>>(src, dst, n4);
}